// Round 1
// baseline (171887.036 us; speedup 1.0000x reference)
//
#include <hip/hip_runtime.h>

// Adaptive binary arithmetic decoder (inherently serial).
// Strategy: 256-thread prologue packs payload bits into LDS + inits model,
// then lane 0 runs the serial decode with a register bit-window and
// double-precision-assisted exact integer division.

#define WORDS_LDS 16384   // 16384 * 32 bits = 524288 bits = 64 KiB LDS
#define MAX_STATES 1024   // context_bits up to 10; actual = 8 -> 256 states

// floor(n/d) for 0 <= n < 2^45, 0 < d < 2^45 (both exact in double).
// Double division is correctly rounded -> truncated quotient off by at most 1.
__device__ __forceinline__ long long ddiv_floor(long long n, long long d) {
    double qd = (double)n / (double)d;
    long long q = (long long)qd;
    long long r = n - q * d;
    if (r < 0)       { q -= 1; }
    else if (r >= d) { q += 1; }
    return q;
}

__global__ __launch_bounds__(256)
void EntropyDecoder_84928683311460_kernel(
    const int* __restrict__ bits,   // payload bits {0,1}
    const int* __restrict__ tf_p,   // total_freq (scalar)
    const int* __restrict__ ns_p,   // num_symbols (scalar)
    const int* __restrict__ cb_p,   // context_bits (scalar)
    float* __restrict__ out,
    int nb)                         // number of payload bits
{
    __shared__ unsigned words[WORDS_LDS];  // MSB-first packed bits
    __shared__ int2 cnt[MAX_STATES];       // .x = count0, .y = count1

    const int tid = threadIdx.x;
    const long long total_freq = (long long)(*tf_p);
    const int num_symbols = *ns_p;
    const int context_bits = *cb_p;
    const int num_states = 1 << context_bits;
    const int smask = num_states - 1;

    const int nwords = (nb + 31) >> 5;
    const int nwords_lds = nwords < WORDS_LDS ? nwords : WORDS_LDS;

    // ---- parallel: pack bits into LDS, MSB-first per 32-bit word ----
    for (int w = tid; w < nwords_lds; w += blockDim.x) {
        unsigned v = 0;
        int base = w << 5;
        if (base + 32 <= nb) {
            #pragma unroll
            for (int j = 0; j < 32; j += 4) {
                int4 b4 = *reinterpret_cast<const int4*>(bits + base + j);
                v |= ((unsigned)(b4.x & 1) << (31 - j))
                   | ((unsigned)(b4.y & 1) << (30 - j))
                   | ((unsigned)(b4.z & 1) << (29 - j))
                   | ((unsigned)(b4.w & 1) << (28 - j));
            }
        } else {
            for (int j = 0; j < 32; ++j) {
                int idx = base + j;
                int b = (idx < nb) ? (bits[idx] & 1) : 0;
                v |= ((unsigned)b) << (31 - j);
            }
        }
        words[w] = v;
    }
    for (int s = tid; s < num_states; s += blockDim.x) cnt[s] = make_int2(1, 1);
    __syncthreads();
    if (tid != 0) return;

    // ---- serial: arithmetic decode on lane 0 ----
    const unsigned long long MASK32   = 0xFFFFFFFFull;
    const unsigned long long HALF     = 0x80000000ull;
    const unsigned long long QUARTER  = 0x40000000ull;
    const unsigned long long THREEQ   = 0xC0000000ull;

    unsigned long long low = 0, high = MASK32;
    unsigned long long bitbuf = 0;   // next payload bits, MSB-first at bit 63
    int navail = 0;                  // valid bits in bitbuf
    long long pos = 0;               // next bit index to load (multiple of 32)

    // refill window to >= 33 valid bits; bits past nb read as 0
    auto refill = [&]() {
        while (navail <= 32) {
            long long widx = pos >> 5;
            unsigned w;
            if (widx < nwords_lds) {
                w = words[widx];
            } else if (widx < nwords) {
                // fallback path (only if payload > 512K bits): gather from HBM
                unsigned g = 0;
                long long base = widx << 5;
                for (int j = 0; j < 32; ++j) {
                    long long idx = base + j;
                    int b = (idx < nb) ? (bits[idx] & 1) : 0;
                    g |= ((unsigned)b) << (31 - j);
                }
                w = g;
            } else {
                w = 0u;
            }
            bitbuf |= ((unsigned long long)w) << (32 - navail);
            navail += 32;
            pos += 32;
        }
    };

    refill();
    unsigned long long code = bitbuf >> 32;  // first 32 bits, MSB-first
    bitbuf <<= 32;
    navail -= 32;

    const long long tfm2 = total_freq - 2;
    const long long tfm1 = total_freq - 1;

    int state = 0;
    for (int s = 0; s < num_symbols; ++s) {
        int2 c = cnt[state];
        long long n0 = c.x;
        long long n1 = c.y;

        // p0_freq: must match jax float64 path bit-exactly (two roundings)
        double p0 = (double)n0 / (double)(n0 + n1);
        double pf = rint(p0 * (double)tfm2) + 1.0;  // v_rndne_f64 = half-even
        long long p0_freq = (long long)pf;
        if (p0_freq < 1)    p0_freq = 1;
        if (p0_freq > tfm1) p0_freq = tfm1;

        unsigned long long rng = high - low + 1;  // in (2^30, 2^32]
        long long num_scaled = (long long)((code - low + 1) * (unsigned long long)total_freq) - 1;
        long long scaled = ddiv_floor(num_scaled, (long long)rng);
        unsigned long long split =
            low + (unsigned long long)ddiv_floor((long long)(rng * (unsigned long long)p0_freq), total_freq);

        int bit = (scaled >= p0_freq) ? 1 : 0;
        if (bit) low = split;
        else     high = split - 1;

        refill();  // guarantees >= 33 bits; max 13 renorms per symbol (tf=4096)

        // E1/E2/E3 renormalization
        for (;;) {
            unsigned long long sub;
            if (high < HALF)                          sub = 0ull;
            else if (low >= HALF)                     sub = HALF;
            else if (low >= QUARTER && high < THREEQ) sub = QUARTER;
            else break;
            low  = ((low  - sub) << 1) & MASK32;
            high = (((high - sub) << 1) & MASK32) | 1ull;
            unsigned b = (unsigned)(bitbuf >> 63);
            code = (((code - sub) << 1) & MASK32) | b;
            bitbuf <<= 1;
            navail--;
        }

        if (bit) cnt[state].y = (int)(n1 + 1);
        else     cnt[state].x = (int)(n0 + 1);
        state = ((state << 1) | bit) & smask;
        out[s] = bit ? 1.0f : -1.0f;
    }
}

extern "C" void kernel_launch(void* const* d_in, const int* in_sizes, int n_in,
                              void* d_out, int out_size, void* d_ws, size_t ws_size,
                              hipStream_t stream) {
    const int* bits = (const int*)d_in[0];
    const int* tf   = (const int*)d_in[1];
    const int* ns   = (const int*)d_in[2];
    const int* cb   = (const int*)d_in[3];
    float* out = (float*)d_out;
    int nb = in_sizes[0];

    hipLaunchKernelGGL(EntropyDecoder_84928683311460_kernel,
                       dim3(1), dim3(256), 0, stream,
                       bits, tf, ns, cb, out, nb);
}

// Round 2
// 87068.536 us; speedup vs baseline: 1.9742x; 1.9742x over previous
//
#include <hip/hip_runtime.h>

// Adaptive binary arithmetic decoder — inherently serial.
// One workgroup: 256-thread prologue packs payload bits + model table into LDS,
// then lane 0 runs the serial decode with:
//   - no integer divisions on the critical path (algebraic transform + pow2 shift)
//   - per-state precomputed p0_freq (f64 chain overlapped with renorm)
//   - prefetched next-state candidates (LDS latency hidden)
//   - branchless batched E1/E2/E3 renormalization via clz

#define WORDS_LDS 16400   // 16384 words = 524288 bits payload + zero pad
#define MAX_STATES 1024

// floor(n/d) for 0 <= n < 2^52, 0 < d < 2^52 both exact in double (cold path).
__device__ __forceinline__ long long ddiv_floor(long long n, long long d) {
    double qd = (double)n / (double)d;
    long long q = (long long)qd;
    long long r = n - q * d;
    q -= (r < 0);
    q += (r >= d);
    return q;
}

template<bool POW2>
__device__ __forceinline__ void decode_serial(
    const unsigned* __restrict__ words, int4* __restrict__ tab,
    const int* __restrict__ bits, int nb,
    long long total_freq, int tf_shift, int num_symbols, int smask,
    float* __restrict__ out)
{
    const unsigned long long M = 0xFFFFFFFFull;
    const unsigned long long H = 0x80000000ull;
    const double tfm2d = (double)(total_freq - 2);
    const int tfm1 = (int)(total_freq - 1);

    unsigned long long low = 0, high = M;
    unsigned long long code = words[0];                  // first 32 bits MSB-first
    unsigned long long bitbuf = (((unsigned long long)words[1]) << 32) | words[2];
    int navail = 64;                                      // valid bits at top of bitbuf
    unsigned pre = words[3];                              // prefetched next word
    int widx = 4;

    int state = 0;
    int4 c = tab[0];
    int n0 = c.x, n1 = c.y, pf = c.z;

    for (int s = 0; s < num_symbols; ++s) {
        // prefetch both next-state candidates (used at the END of this iteration)
        int c0 = (state << 1) & smask;
        int4 q0 = tab[c0];
        int4 q1 = tab[c0 | 1];

        // refill bit window to >= 33 valid bits (max 13 consumed per symbol)
        if (navail <= 32) {
            bitbuf |= ((unsigned long long)pre) << (32 - navail);
            navail += 32;
            unsigned nxt;
            if (widx < WORDS_LDS) {
                nxt = words[widx];          // zero beyond payload (pre-zeroed)
            } else {
                // cold generic fallback for payloads > LDS capacity
                unsigned g = 0;
                long long base = ((long long)widx) << 5;
                for (int j = 0; j < 32; ++j) {
                    long long idx = base + j;
                    int bb = (idx < nb) ? (bits[idx] & 1) : 0;
                    g |= ((unsigned)bb) << (31 - j);
                }
                nxt = g;
            }
            pre = nxt;
            ++widx;
        }

        // ---- decode one bit (no division) ----
        unsigned long long rng = high - low + 1;          // in (2^30, 2^32]
        unsigned long long P = (unsigned long long)(unsigned)pf * rng;   // < 2^44
        unsigned long long dlt = code - low + 1;
        unsigned long long N = POW2 ? ((dlt << tf_shift) - 1ull)
                                    : (dlt * (unsigned long long)total_freq - 1ull);
        int bit = (N >= P) ? 1 : 0;   // == (floor(N/rng) >= p0_freq)
        unsigned long long soff = POW2 ? (P >> tf_shift)
                                       : (unsigned long long)ddiv_floor((long long)P, total_freq);
        unsigned long long split = low + soff;
        low  = bit ? split : low;
        high = bit ? high : (split - 1ull);
        out[s] = bit ? 1.0f : -1.0f;

        // ---- model update: start f64 chain now; it overlaps the renorm below ----
        int nn0 = n0 + 1 - bit;
        int nn1 = n1 + bit;
        double p0d = (double)nn0 / (double)(nn0 + nn1);   // IEEE-exact, matches jax f64
        double pfd = rint(p0d * tfm2d) + 1.0;             // v_rndne_f64 = round-half-even
        int pfn = (int)pfd;
        pfn = pfn < 1 ? 1 : pfn;
        pfn = pfn > tfm1 ? tfm1 : pfn;

        // ---- batched renormalization (branchless; linear mod 2^32) ----
        // E1/E2: shift out all shared top bits at once
        unsigned x = (unsigned)(low ^ high);
        int k = __builtin_clzll((((unsigned long long)x) << 32) | 1ull);  // clz32(x), 32+ if x==0
        k = k > 32 ? 32 : k;
        low  = (low << k) & M;
        high = ((high << k) | ((1ull << k) - 1ull)) & M;
        unsigned long long tk = (bitbuf >> (63 - k)) >> 1;   // next k stream bits (0 if k==0)
        code = ((code << k) & M) | tk;
        bitbuf <<= k;
        navail -= k;
        // E3: underflow expansion, m = min(leading ones of low after top,
        //                                  leading zeros of high after top)
        unsigned l32 = (unsigned)low, h32 = (unsigned)high;
        int a = __builtin_clz(~(l32 << 1));      // bit0 of arg is 1 -> never zero
        int b = __builtin_clz((h32 << 1) | 1u);  // |1 keeps arg nonzero
        int m = a < b ? a : b;                   // 0..31
        unsigned long long ones = (1ull << m) - 1ull;
        low  = ((low << m) - ones * H) & M;                 // l_m = 2^m l - (2^m-1)H
        high = ((high << m) - ones * (H - 1ull)) & M;       // h_m = 2^m h - (2^m-1)(H-1)
        unsigned long long tm = (bitbuf >> (63 - m)) >> 1;
        code = ((code << m) - ones * H + tm) & M;           // + m stream bits
        bitbuf <<= m;
        navail -= m;

        // write back model late (ds_write waits on pfn, but nothing waits on it)
        tab[state] = make_int4(nn0, nn1, pfn, 0);

        // ---- select next state; forward this iteration's update on self-loop ----
        int nidx = c0 | bit;
        int4 q;
        q.x = bit ? q1.x : q0.x;
        q.y = bit ? q1.y : q0.y;
        q.z = bit ? q1.z : q0.z;
        if (nidx == state) { q.x = nn0; q.y = nn1; q.z = pfn; }  // rare (state 0/255 runs)
        state = nidx;
        n0 = q.x; n1 = q.y; pf = q.z;
    }
}

__global__ __launch_bounds__(256)
void EntropyDecoder_84928683311460_kernel(
    const int* __restrict__ bits,   // payload bits {0,1}
    const int* __restrict__ tf_p,   // total_freq
    const int* __restrict__ ns_p,   // num_symbols
    const int* __restrict__ cb_p,   // context_bits
    float* __restrict__ out,
    int nb)
{
    __shared__ unsigned words[WORDS_LDS];
    __shared__ int4 tab[MAX_STATES];   // {count0, count1, p0_freq, pad}

    const int tid = threadIdx.x;
    const long long total_freq = (long long)(*tf_p);
    const int num_symbols = *ns_p;
    const int context_bits = *cb_p;
    const int num_states = 1 << context_bits;
    const int smask = num_states - 1;

    // ---- parallel: pack bits into LDS, MSB-first; zero-pad the tail ----
    for (int w = tid; w < WORDS_LDS; w += blockDim.x) {
        unsigned v = 0;
        int base = w << 5;
        if (base + 32 <= nb) {
            #pragma unroll
            for (int j = 0; j < 32; j += 4) {
                int4 b4 = *reinterpret_cast<const int4*>(bits + base + j);
                v |= ((unsigned)(b4.x & 1) << (31 - j))
                   | ((unsigned)(b4.y & 1) << (30 - j))
                   | ((unsigned)(b4.z & 1) << (29 - j))
                   | ((unsigned)(b4.w & 1) << (28 - j));
            }
        } else if (base < nb) {
            for (int j = 0; j < 32; ++j) {
                int idx = base + j;
                int b = (idx < nb) ? (bits[idx] & 1) : 0;
                v |= ((unsigned)b) << (31 - j);
            }
        }
        words[w] = v;
    }
    // init model with counts (1,1) and the matching precomputed p0_freq
    {
        double p0d = 0.5;
        double pfd = rint(p0d * (double)(total_freq - 2)) + 1.0;
        int pf0 = (int)pfd;
        int tfm1 = (int)(total_freq - 1);
        pf0 = pf0 < 1 ? 1 : (pf0 > tfm1 ? tfm1 : pf0);
        for (int st = tid; st < num_states; st += blockDim.x)
            tab[st] = make_int4(1, 1, pf0, 0);
    }
    __syncthreads();
    if (tid != 0) return;

    int tf_shift = 31 - __builtin_clz((unsigned)total_freq);
    if ((total_freq & (total_freq - 1)) == 0)
        decode_serial<true >(words, tab, bits, nb, total_freq, tf_shift, num_symbols, smask, out);
    else
        decode_serial<false>(words, tab, bits, nb, total_freq, tf_shift, num_symbols, smask, out);
}

extern "C" void kernel_launch(void* const* d_in, const int* in_sizes, int n_in,
                              void* d_out, int out_size, void* d_ws, size_t ws_size,
                              hipStream_t stream) {
    const int* bits = (const int*)d_in[0];
    const int* tf   = (const int*)d_in[1];
    const int* ns   = (const int*)d_in[2];
    const int* cb   = (const int*)d_in[3];
    float* out = (float*)d_out;
    int nb = in_sizes[0];

    hipLaunchKernelGGL(EntropyDecoder_84928683311460_kernel,
                       dim3(1), dim3(256), 0, stream,
                       bits, tf, ns, cb, out, nb);
}

// Round 3
// 81133.618 us; speedup vs baseline: 2.1186x; 1.0731x over previous
//
#include <hip/hip_runtime.h>

// Adaptive binary arithmetic decoder — inherently serial; one wave, lane 0.
// Round-3 structure:
//   - all range-coder state in 32-bit regs (mod-2^32 truncation = free masking)
//   - fused one-shot renorm: K = k(E1/E2) + m(E3), single shift + single
//     13-bit stream extraction (algebraically identical to the verified
//     iterated form)
//   - model entry packed to 8B {n0, n1|pf<<20}; both next-state candidates
//     fetched with one ds_read_b128 at the top of the iteration
//   - model ds_write DELAYED one iteration + 2-deep register forwarding, so
//     the f64 p0_freq chain (div/mul/rint, must match JAX bit-exactly) is
//     off the in-order-issue critical path

#define WORDS_LDS 16400   // 16384 payload words + zero pad
#define MAX_STATES 1024

__device__ __forceinline__ long long ddiv_floor(long long n, long long d) {
    double qd = (double)n / (double)d;
    long long q = (long long)qd;
    long long r = n - q * d;
    q -= (r < 0);
    q += (r >= d);
    return q;
}

template<bool POW2>
__device__ __forceinline__ void decode_serial(
    const unsigned* __restrict__ words, unsigned* tab,
    const int* __restrict__ bits, int nb, int nwords,
    unsigned total_freq, int tf_shift, int num_symbols, int smask,
    unsigned pf0, float* __restrict__ out)
{
    const unsigned H = 0x80000000u;
    unsigned low = 0u, high = 0xFFFFFFFFu;
    unsigned code = words[0];
    unsigned long long bitbuf = (((unsigned long long)words[1]) << 32) | (unsigned long long)words[2];
    int navail = 64;                 // valid bits at top of bitbuf
    unsigned pre = words[3];         // prefetched next word
    int widx = 4;

    const double tfm2d = (double)(total_freq - 2u);
    const int tfm1 = (int)(total_freq - 1u);

    int state = 0;
    unsigned n0 = 1u, n1 = 1u, pf = pf0;

    // pending (delayed) model write from the previous iteration
    int wIdx = 0;
    unsigned wN0 = 1u, wN1 = 1u, wPf = pf0;   // benign rewrite of tab[0] at iter 0

    float* op = out;

    for (int s = 0; s < num_symbols; ++s) {
        // ---- fetch both children of the current state (consumed at bottom) ----
        const int c0 = (state << 1) & smask;
        uint4 q = *reinterpret_cast<const uint4*>(tab + 2 * c0);  // ds_read_b128

        // ---- refill bit window to >= 33 valid bits (max 13 consumed/iter) ----
        if (navail <= 32) {
            bitbuf |= ((unsigned long long)pre) << (32 - navail);
            navail += 32;
            unsigned nxt = 0u;
            if (widx < WORDS_LDS) {
                nxt = words[widx];          // zero-padded past payload
            } else if (widx < nwords) {     // cold fallback: payload > LDS capacity
                unsigned g = 0u;
                long long base = ((long long)widx) << 5;
                for (int j = 0; j < 32; ++j) {
                    long long idx = base + j;
                    int b = (idx < (long long)nb) ? (bits[idx] & 1) : 0;
                    g |= ((unsigned)b) << (31 - j);
                }
                nxt = g;
            }
            pre = nxt;
            ++widx;
        }

        // ---- bit decision (all 32-bit; P = pf*rng via one 32x32->64 mad) ----
        const unsigned rngm1 = high - low;                     // rng-1 (rng<=2^32)
        const unsigned long long P = (unsigned long long)pf * rngm1 + pf;  // pf*rng < 2^44
        const unsigned dlt = code - low;                       // code-low
        const unsigned long long N = POW2
            ? ((((unsigned long long)dlt) << tf_shift) + (unsigned long long)tfm1)
            : ((unsigned long long)dlt * total_freq + (unsigned long long)(total_freq - 1u));
        const int bit = (N >= P) ? 1 : 0;   // == (floor(N/rng) >= p0_freq)
        const unsigned soff = POW2 ? (unsigned)(P >> tf_shift)
                                   : (unsigned)ddiv_floor((long long)P, (long long)total_freq);
        const unsigned split = low + soff;
        low  = bit ? split : low;
        high = bit ? high : (split - 1u);
        *op++ = bit ? 1.0f : -1.0f;

        // ---- model update; f64 chain result not consumed for >= 1 iteration ----
        const unsigned nn0 = n0 + (unsigned)(1 - bit);
        const unsigned nn1 = n1 + (unsigned)bit;
        double p0d = (double)(int)nn0 / (double)(int)(nn0 + nn1);  // match JAX: div,
        double pfd = rint(p0d * tfm2d) + 1.0;                      // mul, rint (half-even)
        int pfi = (int)pfd;
        pfi = pfi < 1 ? 1 : (pfi > tfm1 ? tfm1 : pfi);
        const unsigned pfn = (unsigned)pfi;

        // ---- fused renorm: K = k (E1/E2) + m (E3), one combined shift ----
        const unsigned x = low ^ high;           // != 0 (range > 2^18)
        const int k = __builtin_clz(x);          // E1/E2 count, <= 13
        const unsigned aa = ~(low << (k + 1));   // leading ones of low past top
        const unsigned bb = (high << (k + 1)) | ((2u << k) - 1u);
        const int ca = __builtin_clz(aa);
        const int cb = __builtin_clz(bb);
        const int m = ca < cb ? ca : cb;         // E3 count, k+m <= 13
        const int K = k + m;
        const unsigned sub = (m != 0) ? H : 0u;  // (2^m-1)*H mod 2^32
        const unsigned ones = (1u << K) - 1u;
        const unsigned t13 = (unsigned)(bitbuf >> 51);   // top 13 stream bits
        const unsigned tK = t13 >> (13 - K);             // next K bits
        low  = (low << K) - sub;
        high = (high << K) + ones - sub;
        code = ((code << K) | tK) - sub;
        bitbuf <<= K;
        navail -= K;

        // ---- next state: select + 2-deep forward ----
        const int nidx = c0 | bit;
        const unsigned sw0 = bit ? q.z : q.x;
        const unsigned sw1 = bit ? q.w : q.y;
        const bool f2 = (nidx == wIdx);          // stale w.r.t. pending write only
        unsigned xn0 = f2 ? wN0 : sw0;
        unsigned xn1 = f2 ? wN1 : (sw1 & 0xFFFFFu);
        unsigned xpf = f2 ? wPf : (sw1 >> 20);

        // delayed write of the PREVIOUS iteration's update (wPf long ready)
        *reinterpret_cast<uint2*>(tab + 2 * wIdx) = make_uint2(wN0, wN1 | (wPf << 20));

        // rotate pending (regalloc coalesces; pfn still in flight is fine)
        wIdx = state; wN0 = nn0; wN1 = nn1; wPf = pfn;

        // self-loop (states 0/255 only, rare): real branch so the common path
        // never reads the in-flight pfn
        if (__builtin_expect(nidx == state, 0)) {
            asm volatile("");
            xn0 = nn0; xn1 = nn1; xpf = pfn;
        }
        state = nidx;
        n0 = xn0; n1 = xn1; pf = xpf;
    }
}

__global__ __launch_bounds__(256)
void EntropyDecoder_84928683311460_kernel(
    const int* __restrict__ bits,
    const int* __restrict__ tf_p,
    const int* __restrict__ ns_p,
    const int* __restrict__ cb_p,
    float* __restrict__ out,
    int nb)
{
    __shared__ unsigned words[WORDS_LDS];
    __shared__ __align__(16) unsigned tab[MAX_STATES * 2];  // {n0, n1|pf<<20}

    const int tid = threadIdx.x;
    const unsigned total_freq = (unsigned)(*tf_p);
    const int num_symbols = *ns_p;
    const int context_bits = *cb_p;
    const int num_states = 1 << context_bits;
    const int smask = num_states - 1;
    const int nwords = (nb + 31) >> 5;

    // ---- parallel: pack payload bits MSB-first into LDS; zero-pad tail ----
    for (int w = tid; w < WORDS_LDS; w += blockDim.x) {
        unsigned v = 0;
        int base = w << 5;
        if (base + 32 <= nb) {
            #pragma unroll
            for (int j = 0; j < 32; j += 4) {
                int4 b4 = *reinterpret_cast<const int4*>(bits + base + j);
                v |= ((unsigned)(b4.x & 1) << (31 - j))
                   | ((unsigned)(b4.y & 1) << (30 - j))
                   | ((unsigned)(b4.z & 1) << (29 - j))
                   | ((unsigned)(b4.w & 1) << (28 - j));
            }
        } else if (base < nb) {
            for (int j = 0; j < 32; ++j) {
                int idx = base + j;
                int b = (idx < nb) ? (bits[idx] & 1) : 0;
                v |= ((unsigned)b) << (31 - j);
            }
        }
        words[w] = v;
    }
    // ---- init model: counts (1,1) and matching p0_freq ----
    unsigned pf0;
    {
        double pfd = rint(0.5 * (double)(total_freq - 2u)) + 1.0;
        int t = (int)pfd;
        int tfm1 = (int)(total_freq - 1u);
        t = t < 1 ? 1 : (t > tfm1 ? tfm1 : t);
        pf0 = (unsigned)t;
    }
    for (int st = tid; st < num_states; st += blockDim.x) {
        tab[2 * st]     = 1u;
        tab[2 * st + 1] = 1u | (pf0 << 20);
    }
    __syncthreads();
    if (tid != 0) return;

    const int tf_shift = 31 - __builtin_clz(total_freq);
    if ((total_freq & (total_freq - 1u)) == 0u)
        decode_serial<true >(words, tab, bits, nb, nwords, total_freq, tf_shift,
                             num_symbols, smask, pf0, out);
    else
        decode_serial<false>(words, tab, bits, nb, nwords, total_freq, tf_shift,
                             num_symbols, smask, pf0, out);
}

extern "C" void kernel_launch(void* const* d_in, const int* in_sizes, int n_in,
                              void* d_out, int out_size, void* d_ws, size_t ws_size,
                              hipStream_t stream) {
    const int* bits = (const int*)d_in[0];
    const int* tf   = (const int*)d_in[1];
    const int* ns   = (const int*)d_in[2];
    const int* cb   = (const int*)d_in[3];
    float* out = (float*)d_out;
    int nb = in_sizes[0];

    hipLaunchKernelGGL(EntropyDecoder_84928683311460_kernel,
                       dim3(1), dim3(256), 0, stream,
                       bits, tf, ns, cb, out, nb);
}

// Round 5
// 79844.263 us; speedup vs baseline: 2.1528x; 1.0161x over previous
//
#include <hip/hip_runtime.h>

// Adaptive binary arithmetic decoder — inherently serial; one wave, lane 0.
// Round-4 structure (resubmission — previous round hit GPU acquisition timeout):
//   - p0_freq via exact INTEGER round-to-nearest: floor((8188*n0+t)/(2t)),
//     division done with v_rcp_f32 + umul24 + 1-step fixup (~45cy vs ~180cy
//     f64 chain). Exact .5 ties (remainder==0) take a rare real branch that
//     replicates the reference f64 double-rounding bit-for-bit.
//   - bit decision reduced to 32-bit compare: bit = (code-low) >= soff,
//     soff = (pf*rng)>>tf_shift  (algebraic identity, no 64-bit N)
//   - fused one-shot renorm, m via single clz(a|b); 14-bit extraction
//     (worst case K=14: post-decode rng>=2^18, renorm doubles to <=2^32)
//   - model ds_write delayed one iteration + 2-deep register forwarding
//   - output bits packed into LDS; parallel 256-thread float expansion epilogue

#define WORDS_LDS 16400   // 16384 payload words + zero pad (524288 bits)
#define MAX_STATES 1024
#define OBITS_WORDS 8192  // 262144 packed output bits

__device__ __forceinline__ long long ddiv_floor(long long n, long long d) {
    double qd = (double)n / (double)d;
    long long q = (long long)qd;
    long long r = n - q * d;
    q -= (r < 0);
    q += (r >= d);
    return q;
}

template<bool FAST>
__device__ __forceinline__ void decode_serial(
    const unsigned* __restrict__ words, unsigned* tab, unsigned* obits,
    const int* __restrict__ bits, int nb, int nwords,
    unsigned total_freq, int tf_shift, int num_symbols, int smask,
    unsigned pf0, float* __restrict__ out)
{
    const unsigned H = 0x80000000u;
    unsigned low = 0u, high = 0xFFFFFFFFu;
    unsigned code = words[0];
    unsigned long long bitbuf = (((unsigned long long)words[1]) << 32) | (unsigned long long)words[2];
    int navail = 64;                 // valid bits at top of bitbuf
    unsigned pre = words[3];         // prefetched next word
    int widx = 4;

    const double tfm2d = (double)(total_freq - 2u);
    const int tfm1 = (int)(total_freq - 1u);
    const unsigned tfm2_2 = (total_freq - 2u) << 1;   // 8188 for tf=4096
    constexpr int EXT = FAST ? 14 : 30;               // max renorm bits/symbol

    int state = 0;
    unsigned n0 = 1u, n1 = 1u, pf = pf0;

    // pending (delayed) model write from the previous iteration
    int wIdx = 0;
    unsigned wN0 = 1u, wN1 = 1u, wPf = pf0;

    unsigned obuf = 0u;

    for (int s = 0; s < num_symbols; ++s) {
        // ---- fetch both children of the current state (consumed at bottom) ----
        const int c0 = (state << 1) & smask;
        uint4 q = *reinterpret_cast<const uint4*>(tab + 2 * c0);  // ds_read_b128

        // ---- refill bit window to >= 33 valid bits (max EXT consumed/iter) ----
        if (navail <= 32) {
            bitbuf |= ((unsigned long long)pre) << (32 - navail);
            navail += 32;
            unsigned nxt = 0u;
            if (widx < WORDS_LDS) {
                nxt = words[widx];          // zero-padded past payload
            } else if (widx < nwords) {     // cold fallback: payload > LDS capacity
                unsigned g = 0u;
                long long base = ((long long)widx) << 5;
                for (int j = 0; j < 32; ++j) {
                    long long idx = base + j;
                    int b = (idx < (long long)nb) ? (bits[idx] & 1) : 0;
                    g |= ((unsigned)b) << (31 - j);
                }
                nxt = g;
            }
            pre = nxt;
            ++widx;
        }

        // ---- bit decision: bit = (code-low >= soff), soff = floor(pf*rng/tf) ----
        const unsigned rngm1 = high - low;                              // rng-1
        const unsigned long long P = (unsigned long long)pf * rngm1 + pf;  // pf*rng < 2^44
        const unsigned soff = FAST ? (unsigned)(P >> tf_shift)
                                   : (unsigned)ddiv_floor((long long)P, (long long)total_freq);
        const unsigned dlt = code - low;
        const int bit = (dlt >= soff) ? 1 : 0;
        const unsigned split = low + soff;
        low  = bit ? split : low;
        high = bit ? high : (split - 1u);
        obuf = (obuf << 1) | (unsigned)bit;

        // ---- model update: p0_freq without f64 on the hot path ----
        const unsigned nn0 = n0 + (unsigned)(1 - bit);
        const unsigned nn1 = n1 + (unsigned)bit;
        unsigned pfn;
        if (FAST) {
            const unsigned t  = nn0 + nn1;
            const unsigned d2 = t << 1;
            const unsigned num2 = __umul24(tfm2_2, nn0) + t;   // 8188*n0 + t < 2^31
            const float qf = (float)num2 * __builtin_amdgcn_rcpf((float)d2);
            unsigned qi = (unsigned)qf;                        // |err| < 1e-3 pre-trunc
            int r = (int)(num2 - __umul24(qi, d2));
            if (r < 0)          { qi -= 1u; r += (int)d2; }    // cndmask fixups
            if (r >= (int)d2)   { qi += 1u; r -= (int)d2; }
            pfn = qi + 1u;                                     // = rint(x)+1, non-tie
            if (__builtin_expect(r == 0, 0)) {
                // exact .5 tie: replicate reference f64 double-rounding exactly
                asm volatile("");
                double p0d = (double)(int)nn0 / (double)(int)t;
                double pfd = rint(p0d * tfm2d) + 1.0;
                int pfi = (int)pfd;
                pfi = pfi < 1 ? 1 : (pfi > tfm1 ? tfm1 : pfi);
                pfn = (unsigned)pfi;
            }
        } else {
            double p0d = (double)(int)nn0 / (double)(int)(nn0 + nn1);
            double pfd = rint(p0d * tfm2d) + 1.0;
            int pfi = (int)pfd;
            pfi = pfi < 1 ? 1 : (pfi > tfm1 ? tfm1 : pfi);
            pfn = (unsigned)pfi;
        }

        // ---- fused renorm: K = k (E1/E2) + m (E3), one combined shift ----
        const unsigned x = low ^ high;             // != 0
        const int k = __builtin_clz(x);
        const unsigned aa = ~(low << (k + 1));     // != 0 (trailing ones)
        const unsigned bb = (high << (k + 1)) | ((2u << k) - 1u);  // != 0
        const int m = __builtin_clz(aa | bb);      // = min(clz(aa), clz(bb))
        const int K = k + m;
        const unsigned sub = (m != 0) ? H : 0u;    // (2^m-1)*H mod 2^32
        const unsigned ones = (1u << K) - 1u;
        const unsigned tE = (unsigned)(bitbuf >> (64 - EXT));
        const unsigned tK = tE >> (EXT - K);       // next K stream bits
        low  = (low << K) - sub;
        high = (high << K) + ones - sub;
        code = ((code << K) | tK) - sub;
        bitbuf <<= K;
        navail -= K;

        // ---- next state: select + 2-deep forward ----
        const int nidx = c0 | bit;
        const unsigned sw0 = bit ? q.z : q.x;
        const unsigned sw1 = bit ? q.w : q.y;
        const bool f2 = (nidx == wIdx);            // stale w.r.t. pending write
        unsigned xn0 = f2 ? wN0 : sw0;
        unsigned xn1 = f2 ? wN1 : (sw1 & 0xFFFFFu);
        unsigned xpf = f2 ? wPf : (sw1 >> 20);

        // delayed write of the PREVIOUS iteration's update (wPf long ready)
        *reinterpret_cast<uint2*>(tab + 2 * wIdx) = make_uint2(wN0, wN1 | (wPf << 20));
        wIdx = state; wN0 = nn0; wN1 = nn1; wPf = pfn;

        // self-loop (rare): real branch so common path never waits on pfn
        if (__builtin_expect(nidx == state, 0)) {
            asm volatile("");
            xn0 = nn0; xn1 = nn1; xpf = pfn;
        }
        state = nidx;
        n0 = xn0; n1 = xn1; pf = xpf;

        // ---- pack output bit; flush every 32 symbols (scalar branch) ----
        if ((s & 31) == 31) {
            int wo = s >> 5;
            if (wo < OBITS_WORDS) {
                obits[wo] = obuf;
            } else {                                // cold overflow: direct store
                int base = s & ~31;
                for (int j = 0; j < 32; ++j)
                    out[base + j] = ((obuf >> (31 - j)) & 1u) ? 1.0f : -1.0f;
            }
        }
    }
    if (num_symbols & 31) {                         // generic tail flush
        int rem = num_symbols & 31;
        unsigned v = obuf << (32 - rem);
        int wo = num_symbols >> 5;
        if (wo < OBITS_WORDS) {
            obits[wo] = v;
        } else {
            int base = num_symbols & ~31;
            for (int j = 0; j < rem; ++j)
                out[base + j] = ((v >> (31 - j)) & 1u) ? 1.0f : -1.0f;
        }
    }
}

__global__ __launch_bounds__(256)
void EntropyDecoder_84928683311460_kernel(
    const int* __restrict__ bits,
    const int* __restrict__ tf_p,
    const int* __restrict__ ns_p,
    const int* __restrict__ cb_p,
    float* __restrict__ out,
    int nb)
{
    __shared__ unsigned words[WORDS_LDS];
    __shared__ __align__(16) unsigned tab[MAX_STATES * 2];  // {n0, n1|pf<<20}
    __shared__ unsigned obits[OBITS_WORDS];                 // packed output bits

    const int tid = threadIdx.x;
    const unsigned total_freq = (unsigned)(*tf_p);
    const int num_symbols = *ns_p;
    const int context_bits = *cb_p;
    const int num_states = 1 << context_bits;
    const int smask = num_states - 1;
    const int nwords = (nb + 31) >> 5;

    // ---- parallel: pack payload bits MSB-first into LDS; zero-pad tail ----
    for (int w = tid; w < WORDS_LDS; w += blockDim.x) {
        unsigned v = 0;
        int base = w << 5;
        if (base + 32 <= nb) {
            #pragma unroll
            for (int j = 0; j < 32; j += 4) {
                int4 b4 = *reinterpret_cast<const int4*>(bits + base + j);
                v |= ((unsigned)(b4.x & 1) << (31 - j))
                   | ((unsigned)(b4.y & 1) << (30 - j))
                   | ((unsigned)(b4.z & 1) << (29 - j))
                   | ((unsigned)(b4.w & 1) << (28 - j));
            }
        } else if (base < nb) {
            for (int j = 0; j < 32; ++j) {
                int idx = base + j;
                int b = (idx < nb) ? (bits[idx] & 1) : 0;
                v |= ((unsigned)b) << (31 - j);
            }
        }
        words[w] = v;
    }
    // ---- init model: counts (1,1) and matching p0_freq ----
    unsigned pf0;
    {
        double pfd = rint(0.5 * (double)(total_freq - 2u)) + 1.0;
        int t = (int)pfd;
        int tfm1 = (int)(total_freq - 1u);
        t = t < 1 ? 1 : (t > tfm1 ? tfm1 : t);
        pf0 = (unsigned)t;
    }
    for (int st = tid; st < num_states; st += blockDim.x) {
        tab[2 * st]     = 1u;
        tab[2 * st + 1] = 1u | (pf0 << 20);
    }
    __syncthreads();

    if (tid == 0) {
        const int tf_shift = 31 - __builtin_clz(total_freq);
        const bool pow2 = (total_freq & (total_freq - 1u)) == 0u;
        const unsigned long long bound =
            2ull * (unsigned long long)(total_freq - 2u) * (unsigned long long)(num_symbols + 1)
            + (unsigned long long)(num_symbols + 2);
        const bool fast = pow2 && total_freq >= 8u && total_freq <= 4096u
                          && bound < (1ull << 31);
        if (fast)
            decode_serial<true >(words, tab, obits, bits, nb, nwords, total_freq,
                                 tf_shift, num_symbols, smask, pf0, out);
        else
            decode_serial<false>(words, tab, obits, bits, nb, nwords, total_freq,
                                 tf_shift, num_symbols, smask, pf0, out);
    }
    __syncthreads();

    // ---- parallel epilogue: expand packed bits -> {-1,+1} floats ----
    const int nwout = (num_symbols + 31) >> 5;
    const int npk = nwout < OBITS_WORDS ? nwout : OBITS_WORDS;
    for (int w = tid; w < npk; w += blockDim.x) {
        unsigned v = obits[w];
        int base = w << 5;
        if (base + 32 <= num_symbols) {
            #pragma unroll
            for (int j = 0; j < 32; j += 4) {
                float4 o;
                o.x = ((v >> (31 - j)) & 1u) ? 1.0f : -1.0f;
                o.y = ((v >> (30 - j)) & 1u) ? 1.0f : -1.0f;
                o.z = ((v >> (29 - j)) & 1u) ? 1.0f : -1.0f;
                o.w = ((v >> (28 - j)) & 1u) ? 1.0f : -1.0f;
                *reinterpret_cast<float4*>(out + base + j) = o;
            }
        } else {
            for (int j = 0; j < 32 && base + j < num_symbols; ++j)
                out[base + j] = ((v >> (31 - j)) & 1u) ? 1.0f : -1.0f;
        }
    }
}

extern "C" void kernel_launch(void* const* d_in, const int* in_sizes, int n_in,
                              void* d_out, int out_size, void* d_ws, size_t ws_size,
                              hipStream_t stream) {
    const int* bits = (const int*)d_in[0];
    const int* tf   = (const int*)d_in[1];
    const int* ns   = (const int*)d_in[2];
    const int* cb   = (const int*)d_in[3];
    float* out = (float*)d_out;
    int nb = in_sizes[0];

    hipLaunchKernelGGL(EntropyDecoder_84928683311460_kernel,
                       dim3(1), dim3(256), 0, stream,
                       bits, tf, ns, cb, out, nb);
}